// Round 10
// baseline (166.496 us; speedup 1.0000x reference)
//
#include <hip/hip_runtime.h>
#include <stdint.h>
#include <math.h>

#pragma clang fp contract(off)

#define N_ROWS 1048576
#define N_CLS  20
#define K_TOP  2000
#define CAND_MAX 8192
#define NBINS  4096
#define H_COPIES 4
#define DELTA_ULP 4096u
#define MAGIC 0x5AD0C0DEu

// scal slots (dwords) -- inside the zeroed region
#define SC_CNT   0
#define SC_MAXK  1
#define SC_DONE  2   // maskscan done-counter

// ws layout
static constexpr size_t OFF_MKEY = 0;                              // u32[N]          4 MB
static constexpr size_t OFF_CLS  = OFF_MKEY + 4ull * N_ROWS;       // u8[N]           1 MB
static constexpr size_t OFF_HIST = OFF_CLS + (size_t)N_ROWS;       // u32[4*4096] -- zero region start
static constexpr size_t OFF_SCAL = OFF_HIST + 4ull * H_COPIES * NBINS;  // u32[16]
static constexpr size_t OFF_GRP  = OFF_SCAL + 64;                  // u64[32]     -- zero region end (16464 dw)
static constexpr size_t OFF_ZIN  = OFF_GRP + 256;                  // u32[8] MAGIC words (reset by last kernel)
static constexpr size_t OFF_CAND = OFF_ZIN + 64;                   // u64[CAND_MAX]
static constexpr size_t OFF_MASK = OFF_CAND + 8ull * CAND_MAX;     // u64[K_TOP*32]

__device__ __forceinline__ uint32_t mono_key(float f) {
    uint32_t u = __float_as_uint(f);
    return u ^ ((u & 0x80000000u) ? 0xFFFFFFFFu : 0x80000000u);
}
__device__ __forceinline__ float mono_inv(uint32_t k) {
    uint32_t u = (k & 0x80000000u) ? (k ^ 0x80000000u) : ~k;
    return __uint_as_float(u);
}

// ---- D1: per-row max/argmax of logits (LDS-staged coalesced loads) -> mkey, cls,
//      fused 12-bit histogram (LDS u32[4096] pre-agg, 4 spread global copies).
//      Zeroing by blocks 0..7 via zin-MAGIC handshake (value-semantic, poison-proof).
//      NO min-waves launch_bounds (R7/R9 lesson), NO grid barrier.
__global__ __launch_bounds__(256) void k_score(const float* __restrict__ logits,
                                               uint32_t* __restrict__ mkey,
                                               uint8_t* __restrict__ cls,
                                               uint32_t* __restrict__ hist,   // zero region base
                                               uint32_t* __restrict__ zin) {
    __shared__ uint32_t stage[256 * 21];   // 21.5 KB
    __shared__ uint32_t hh[NBINS];         // 16 KB
    int t = threadIdx.x, b = blockIdx.x;

    // zero phase: blocks 0..7 zero hist(16384 dw) + scal(16) + grp(64) via device atomics
    if (b < 8) {
        uint32_t zd = 0;
        for (int k = 0; k < 8; ++k) zd += atomicExch(&hist[(b * 256 + t) + k * 2048], 0u);
        if (b == 7 && t < 80) zd += atomicExch(&hist[16384 + t], 0u);
        asm volatile("" :: "v"(zd));
        asm volatile("s_waitcnt vmcnt(0)" ::: "memory");
        __syncthreads();
        if (t == 0) atomicExch(&zin[b], MAGIC);
    }

    for (int i = t; i < NBINS; i += 256) hh[i] = 0;
    __syncthreads();
    size_t rowbase0 = (size_t)b * 1024;
    for (int g = 0; g < 4; ++g) {
        const float4* src = (const float4*)(logits + (rowbase0 + (size_t)g * 256) * N_CLS);
#pragma unroll
        for (int q = 0; q < 5; ++q) {
            float4 v = src[q * 256 + t];            // fully coalesced 16B/lane
            int w0 = (q * 256 + t) * 4;
#pragma unroll
            for (int e = 0; e < 4; ++e) {
                int w = w0 + e;                     // stage addr = w + w/20 (row pad 20->21)
                stage[w + ((w * 52429u) >> 20)] = __float_as_uint((&v.x)[e]);
            }
        }
        __syncthreads();
        const uint32_t* row = &stage[t * 21];
        float m = __uint_as_float(row[0]); int ci = 0;
#pragma unroll
        for (int c = 1; c < 20; ++c) {
            float v = __uint_as_float(row[c]);
            if (v > m) { m = v; ci = c; }
        }
        size_t ri = rowbase0 + (size_t)g * 256 + t;
        uint32_t u = mono_key(m);
        mkey[ri] = u;
        cls[ri] = (uint8_t)ci;
        atomicAdd(&hh[u >> 20], 1u);                // 12-bit bin
        __syncthreads();
    }

    // wait for zeroing (normally long done: zero ~1us << compute ~13us)
    for (;;) {
        int ok = 1;
        if (t < 8) ok = (atomicAdd(&zin[t], 0u) == MAGIC) ? 1 : 0;
        if (__syncthreads_count(ok) == 256) break;
        __builtin_amdgcn_s_sleep(16);
    }
    // publish nonzero bins only (4 spread copies); kernel-end drain handles visibility
    uint32_t cp = (uint32_t)((b & (H_COPIES - 1)) << 12);
    for (int i = 0; i < 16; ++i) {
        uint32_t v = hh[t * 16 + i];
        if (v) atomicAdd(&hist[cp + t * 16 + i], v);
    }
}

// ---- D2: per-block redundant 12-bit find -> Tk = (b*<<20) - DELTA_ULP (tie margin),
//      then compact candidates (mkey >= Tk), LDS-staged, 1 global atomic/block.
__global__ __launch_bounds__(256) void k_compact(const uint32_t* __restrict__ mkey,
                                                 const uint32_t* __restrict__ hist,
                                                 uint32_t* __restrict__ scal,
                                                 unsigned long long* __restrict__ cand) {
    __shared__ uint32_t sfx[256];
    __shared__ uint32_t sTk;
    __shared__ uint32_t cnt, gbase;
    __shared__ uint64_t stg[1024];
    int t = threadIdx.x;
    int lane = t & 63;
    if (t == 0) cnt = 0;

    // find12: thread t owns bins [t*16, t*16+16), summed over 4 copies (plain loads,
    // cross-dispatch coherent); suffix-scan over 256 chunk totals; locate rank-K bin.
    uint32_t bv[16]; uint32_t ct = 0;
#pragma unroll
    for (int i = 0; i < 16; ++i) {
        uint32_t s = 0;
#pragma unroll
        for (int k = 0; k < H_COPIES; ++k) s += hist[(k << 12) + t * 16 + i];
        bv[i] = s; ct += s;
    }
    sfx[t] = ct;
    __syncthreads();
    for (int off = 1; off < 256; off <<= 1) {
        uint32_t v = (t + off < 256) ? sfx[t + off] : 0;
        __syncthreads();
        sfx[t] += v;
        __syncthreads();
    }
    if (sfx[t] >= (uint32_t)K_TOP && (t == 255 || sfx[t + 1] < (uint32_t)K_TOP)) {
        uint32_t cum = (t == 255) ? 0u : sfx[t + 1];
        int i = 15;
        for (; i >= 0; --i) { cum += bv[i]; if (cum >= (uint32_t)K_TOP) break; }
        if (i < 0) i = 0;
        uint32_t bstar = (uint32_t)(t * 16 + i);
        uint32_t tk = bstar << 20;
        // δ-ULP margin: covers rounded-sigmoid ties (~11 key-ULPs) with 370x slack,
        // instead of a full -1 bin (which would admit ~7K extra rows at 12-bit).
        sTk = (tk > DELTA_ULP) ? (tk - DELTA_ULP) : 0u;
    }
    __syncthreads();
    uint32_t Tk = sTk;

    const uint4* m4 = (const uint4*)mkey;
    size_t base = (size_t)blockIdx.x * 1024;       // uint4 index; 4096 rows/block
    for (int it = 0; it < 4; ++it) {
        uint32_t r0 = (uint32_t)((base + it * 256 + t) * 4);
        uint4 v = m4[base + it * 256 + t];
#pragma unroll
        for (int e = 0; e < 4; ++e) {
            uint32_t u = (e == 0) ? v.x : (e == 1) ? v.y : (e == 2) ? v.z : v.w;
            bool pass = u >= Tk;
            unsigned long long bal = __ballot(pass);
            if (bal) {
                uint32_t wbase = 0;
                if (lane == 0) wbase = atomicAdd(&cnt, (uint32_t)__popcll(bal));
                wbase = __shfl(wbase, 0);
                if (pass) {
                    uint32_t pos = wbase + (uint32_t)__popcll(bal & ((1ull << lane) - 1ull));
                    if (pos < 1024) stg[pos] = ((uint64_t)u << 32) | (r0 + e);
                }
            }
        }
    }
    __syncthreads();
    uint32_t n = cnt; if (n > 1024) n = 1024;
    if (t == 0 && n) gbase = atomicAdd(&scal[SC_CNT], n);
    __syncthreads();
    if (n) {
        uint32_t gb = gbase;
        for (uint32_t i = t; i < n; i += 256) {
            uint32_t pos = gb + i;
            if (pos < (uint32_t)CAND_MAX) cand[pos] = stg[i];  // plain store; boundary = coherence
        }
    }
}

// ---- D3: rank-by-counting, j-PARALLEL (proven R7/R8): wave-per-candidate, lanes
//      split the scan, shuffle-reduce. Key low20 = row (tie-break: score desc, idx asc).
__global__ __launch_bounds__(256) void k_rank(const unsigned long long* __restrict__ cand,
                                              uint32_t* __restrict__ scal,
                                              const float* __restrict__ deltas,
                                              const float* __restrict__ locs,
                                              const int* __restrict__ stridep,
                                              const uint8_t* __restrict__ cls,
                                              float* __restrict__ out) {
    __shared__ uint64_t keys[CAND_MAX];   // 64 KB
    int t = threadIdx.x;
    uint32_t M = scal[SC_CNT];
    if (M > (uint32_t)CAND_MAX) M = CAND_MAX;
    for (uint32_t i = t; i < M; i += 256) {
        unsigned long long cd = cand[i];
        uint32_t mk = (uint32_t)(cd >> 32);
        uint32_t row = (uint32_t)cd & (N_ROWS - 1);
        float m = mono_inv(mk);
        float ef = (float)exp(-(double)m);          // ~correctly-rounded fp32 expf
        float s = 1.0f / (1.0f + ef);
        keys[i] = ((uint64_t)(~__float_as_uint(s)) << 32) | row;
    }
    __syncthreads();
    int wid = t >> 6, lane = t & 63;
    float stridef = (float)(*stridep);
    float wmx = -3.4e38f;
    for (uint32_t c = (uint32_t)blockIdx.x * 4 + wid; c < M; c += 256) {  // 64 blocks * 4 waves
        uint64_t myk = keys[c];
        uint32_t r = 0;
        for (uint32_t j = lane; j < M; j += 64) r += (keys[j] < myk) ? 1u : 0u;
#pragma unroll
        for (int o = 32; o > 0; o >>= 1) r += __shfl_down(r, o);
        if (lane == 0 && r < (uint32_t)K_TOP) {
            uint32_t row = (uint32_t)myk & (N_ROWS - 1);
            float s = __uint_as_float(~(uint32_t)(myk >> 32));
            float4 dl = ((const float4*)deltas)[row];
            float2 lc = ((const float2*)locs)[row];
            float d0 = dl.x * stridef, d1 = dl.y * stridef, d2 = dl.z * stridef, d3 = dl.w * stridef;
            float b0f = lc.x - d0, b1f = lc.y - d1, b2f = lc.x + d2, b3f = lc.y + d3;
            float4 bx = { b0f, b1f, b2f, b3f };
            *(float4*)&out[4 * r] = bx;
            out[8000 + r] = s;
            out[10000 + r] = (float)cls[row];
            wmx = fmaxf(wmx, fmaxf(fmaxf(b0f, b1f), fmaxf(b2f, b3f)));
        }
    }
    if (lane == 0) atomicMax(&scal[SC_MAXK], mono_key(wmx));
}

// ---- D4: pairwise suppression mask (quirky IoU replicated exactly) + fused scan.
//      Skip-empty rows: mask words written ONLY when the row has any suppression bit;
//      scan reads mask solely for grp-flagged rows (grp zeroed each call), so stale
//      words are never read. Atomic-only handoff (proven R5/R7/R8). Tail: zin reset.
__global__ __launch_bounds__(256) void k_maskscan(const float* __restrict__ out_ro,
                                                  uint32_t* __restrict__ scal,
                                                  uint64_t* __restrict__ mask,
                                                  unsigned long long* __restrict__ grp,
                                                  uint32_t* __restrict__ zin,
                                                  float* __restrict__ out) {
    __shared__ uint64_t wb[4][32];
    __shared__ int lastdone;
    int t = threadIdx.x;
    int lane = t & 63;
    int wid = t >> 6;
    int i = blockIdx.x * 4 + wid;                   // 2000 waves total
    float off1 = mono_inv(scal[SC_MAXK]) + 1.0f;    // max_coord + 1 (prev dispatch, coherent)
    float4 boxi = *(const float4*)&out_ro[4 * i];
    float oi = out_ro[10000 + i] * off1;
    float x1i = boxi.x + oi, y2i = boxi.y + oi, x2i = boxi.z + oi, y1i = boxi.w + oi;
    float ai = (x2i - x1i) * (y2i - y1i);
    uint64_t any = 0;
    for (int jb = 0; jb < 32; ++jb) {
        int j = jb * 64 + lane;
        bool sup = false;
        if (j < K_TOP && j > i) {
            float4 boxj = *(const float4*)&out_ro[4 * j];
            float oj = out_ro[10000 + j] * off1;
            float x1j = boxj.x + oj, y2j = boxj.y + oj, x2j = boxj.z + oj, y1j = boxj.w + oj;
            float aj = (x2j - x1j) * (y2j - y1j);
            float xx1 = fmaxf(x1i, x1j);
            float yy1 = fminf(y1i, y1j);
            float xx2 = fminf(x2i, x2j);
            float yy2 = fmaxf(y2i, y2j);
            float inter = fabsf(xx2 - xx1) * fabsf(yy2 - yy1);
            float iou = inter / ((ai + aj) - inter);
            sup = iou > 0.5f;
        }
        unsigned long long bits = __ballot(sup);
        if (lane == 0) wb[wid][jb] = bits;
        any |= bits;
    }
    unsigned long long dummy = 0;
    if (lane == 0 && any) {                         // rare: NMS barely suppresses here
        for (int jb = 0; jb < 32; ++jb)
            dummy += atomicExch(&mask[(size_t)i * 32 + jb], wb[wid][jb]);
        dummy += atomicOr(&grp[i >> 6], 1ull << (i & 63));
    }
    asm volatile("" :: "v"(dummy));                 // force atomic returns (vmcnt drained)
    asm volatile("s_waitcnt vmcnt(0) lgkmcnt(0)" ::: "memory");
    __syncthreads();
    if (t == 0) {
        unsigned old = atomicAdd(&scal[SC_DONE], 1u);
        lastdone = (old == (unsigned)(gridDim.x - 1)) ? 1 : 0;
    }
    __syncthreads();
    if (!lastdone) return;

    if (t < 64) {
        int l = t;                                  // lane w<32 holds active word w
        uint64_t g = (l < 32) ? atomicOr(&grp[l], 0ull) : 0ull;
        uint64_t active = ~0ull;
        if (__ballot(g != 0ull)) {
            for (int gg = 0; gg < 32; ++gg) {
                uint64_t nz = __shfl(g, gg);
                while (nz) {
                    int b = __ffsll((long long)nz) - 1;
                    nz &= nz - 1;
                    int ii = gg * 64 + b;
                    uint64_t aw = __shfl(active, gg);
                    bool kept = (aw >> b) & 1ull;
                    uint64_t m = (l < 32) ? atomicOr(&mask[(size_t)ii * 32 + l], 0ull) : 0ull;
                    if (kept) active &= ~m;
                }
            }
        }
        if (l < 32) {
            int limit = K_TOP - l * 64;
            int nvec = limit < 64 ? limit / 4 : 16;
            for (int v = 0; v < nvec; ++v) {
                float4 f;
                f.x = ((active >> (4 * v + 0)) & 1ull) ? 1.0f : 0.0f;
                f.y = ((active >> (4 * v + 1)) & 1ull) ? 1.0f : 0.0f;
                f.z = ((active >> (4 * v + 2)) & 1ull) ? 1.0f : 0.0f;
                f.w = ((active >> (4 * v + 3)) & 1ull) ? 1.0f : 0.0f;
                *(float4*)&out[12000 + l * 64 + 4 * v] = f;
            }
        }
    }
    // reset MAGIC words for the next replay (zeroed state is what D1 expects)
    if (t < 8) atomicExch(&zin[t], 0u);
}

extern "C" void kernel_launch(void* const* d_in, const int* in_sizes, int n_in,
                              void* d_out, int out_size, void* d_ws, size_t ws_size,
                              hipStream_t stream) {
    const float* deltas = (const float*)d_in[0];
    const float* locs   = (const float*)d_in[1];
    const float* logits = (const float*)d_in[2];
    const int*   stridep = (const int*)d_in[3];
    float* out = (float*)d_out;
    char* ws = (char*)d_ws;

    uint32_t* mkey = (uint32_t*)(ws + OFF_MKEY);
    uint8_t*  cls  = (uint8_t*)(ws + OFF_CLS);
    uint32_t* hist = (uint32_t*)(ws + OFF_HIST);
    uint32_t* scal = (uint32_t*)(ws + OFF_SCAL);
    unsigned long long* grp = (unsigned long long*)(ws + OFF_GRP);
    uint32_t* zin  = (uint32_t*)(ws + OFF_ZIN);
    unsigned long long* cand = (unsigned long long*)(ws + OFF_CAND);
    uint64_t* mask = (uint64_t*)(ws + OFF_MASK);

    k_score<<<dim3(1024), dim3(256), 0, stream>>>(logits, mkey, cls, hist, zin);
    k_compact<<<dim3(256), dim3(256), 0, stream>>>(mkey, hist, scal, cand);
    k_rank<<<dim3(64), dim3(256), 0, stream>>>(cand, scal, deltas, locs, stridep, cls, out);
    k_maskscan<<<dim3(500), dim3(256), 0, stream>>>(out, scal, mask, grp, zin, out);
}

// Round 11
// 107.962 us; speedup vs baseline: 1.5422x; 1.5422x over previous
//
#include <hip/hip_runtime.h>
#include <stdint.h>
#include <math.h>

#pragma clang fp contract(off)

#define N_ROWS 1048576
#define N_CLS  20
#define K_TOP  2000
#define CAND_MAX 8192
#define NBINS  4096
#define H_COPIES 4
#define DELTA_ULP 4096u
#define MAGIC 0x5AD0C0DEu

// scal slots (dwords) -- inside the zeroed region
#define SC_CNT   0
#define SC_MAXK  1
#define SC_DONE  2   // maskscan done-counter

// ws layout
static constexpr size_t OFF_MKEY = 0;                              // u32[N]          4 MB
static constexpr size_t OFF_CLS  = OFF_MKEY + 4ull * N_ROWS;       // u8[N]           1 MB
static constexpr size_t OFF_HIST = OFF_CLS + (size_t)N_ROWS;       // u32[4*4096] -- zero region start
static constexpr size_t OFF_SCAL = OFF_HIST + 4ull * H_COPIES * NBINS;  // u32[16]
static constexpr size_t OFF_GRP  = OFF_SCAL + 64;                  // u64[32]     -- zero region end (16464 dw)
static constexpr size_t OFF_ZIN  = OFF_GRP + 256;                  // u32[8] MAGIC words (reset by last kernel)
static constexpr size_t OFF_CAND = OFF_ZIN + 64;                   // u64[CAND_MAX]
static constexpr size_t OFF_MASK = OFF_CAND + 8ull * CAND_MAX;     // u64[K_TOP*32]

__device__ __forceinline__ uint32_t mono_key(float f) {
    uint32_t u = __float_as_uint(f);
    return u ^ ((u & 0x80000000u) ? 0xFFFFFFFFu : 0x80000000u);
}
__device__ __forceinline__ float mono_inv(uint32_t k) {
    uint32_t u = (k & 0x80000000u) ? (k ^ 0x80000000u) : ~k;
    return __uint_as_float(u);
}

// ---- D1: per-row max/argmax of logits (LDS-staged coalesced loads) -> mkey, cls,
//      fused 12-bit histogram (LDS u32[4096] pre-agg, 4 spread global copies).
//      Zeroing by blocks 0..7 via zin-MAGIC handshake (value-semantic, poison-proof).
__global__ __launch_bounds__(256) void k_score(const float* __restrict__ logits,
                                               uint32_t* __restrict__ mkey,
                                               uint8_t* __restrict__ cls,
                                               uint32_t* __restrict__ hist,   // zero region base
                                               uint32_t* __restrict__ zin) {
    __shared__ uint32_t stage[256 * 21];   // 21.5 KB
    __shared__ uint32_t hh[NBINS];         // 16 KB
    int t = threadIdx.x, b = blockIdx.x;

    // zero phase: blocks 0..7 zero hist(16384 dw) + scal(16) + grp(64) via device atomics
    if (b < 8) {
        uint32_t zd = 0;
        for (int k = 0; k < 8; ++k) zd += atomicExch(&hist[(b * 256 + t) + k * 2048], 0u);
        if (b == 7 && t < 80) zd += atomicExch(&hist[16384 + t], 0u);
        asm volatile("" :: "v"(zd));
        asm volatile("s_waitcnt vmcnt(0)" ::: "memory");
        __syncthreads();
        if (t == 0) atomicExch(&zin[b], MAGIC);
    }

    for (int i = t; i < NBINS; i += 256) hh[i] = 0;
    __syncthreads();
    size_t rowbase0 = (size_t)b * 1024;
    for (int g = 0; g < 4; ++g) {
        const float4* src = (const float4*)(logits + (rowbase0 + (size_t)g * 256) * N_CLS);
#pragma unroll
        for (int q = 0; q < 5; ++q) {
            float4 v = src[q * 256 + t];            // fully coalesced 16B/lane
            int w0 = (q * 256 + t) * 4;
#pragma unroll
            for (int e = 0; e < 4; ++e) {
                int w = w0 + e;                     // stage addr = w + w/20 (row pad 20->21)
                stage[w + ((w * 52429u) >> 20)] = __float_as_uint((&v.x)[e]);
            }
        }
        __syncthreads();
        const uint32_t* row = &stage[t * 21];
        float m = __uint_as_float(row[0]); int ci = 0;
#pragma unroll
        for (int c = 1; c < 20; ++c) {
            float v = __uint_as_float(row[c]);
            if (v > m) { m = v; ci = c; }
        }
        size_t ri = rowbase0 + (size_t)g * 256 + t;
        uint32_t u = mono_key(m);
        mkey[ri] = u;
        cls[ri] = (uint8_t)ci;
        atomicAdd(&hh[u >> 20], 1u);                // 12-bit bin
        __syncthreads();
    }

    // wait for zeroing (normally long done: zero ~1us << compute ~13us)
    for (;;) {
        int ok = 1;
        if (t < 8) ok = (atomicAdd(&zin[t], 0u) == MAGIC) ? 1 : 0;
        if (__syncthreads_count(ok) == 256) break;
        __builtin_amdgcn_s_sleep(16);
    }
    // publish nonzero bins only (4 spread copies); kernel-end drain handles visibility
    uint32_t cp = (uint32_t)((b & (H_COPIES - 1)) << 12);
    for (int i = 0; i < 16; ++i) {
        uint32_t v = hh[t * 16 + i];
        if (v) atomicAdd(&hist[cp + t * 16 + i], v);
    }
}

// ---- D2: per-block redundant 12-bit find -> Tk = (b*<<20) - DELTA_ULP (tie margin),
//      then compact candidates (mkey >= Tk). NEW: cand[] stores the FINAL sort key
//      ((~sigmoid_bits)<<32 | row) -- sigmoid computed here only for passing rows,
//      so k_rank needs no exp and no per-block key build.
__global__ __launch_bounds__(256) void k_compact(const uint32_t* __restrict__ mkey,
                                                 const uint32_t* __restrict__ hist,
                                                 uint32_t* __restrict__ scal,
                                                 unsigned long long* __restrict__ cand) {
    __shared__ uint32_t sfx[256];
    __shared__ uint32_t sTk;
    __shared__ uint32_t cnt, gbase;
    __shared__ uint64_t stg[1024];
    int t = threadIdx.x;
    int lane = t & 63;
    if (t == 0) cnt = 0;

    // find12: thread t owns bins [t*16, t*16+16), summed over 4 copies; suffix-scan
    // over 256 chunk totals; locate rank-K bin.
    uint32_t bv[16]; uint32_t ct = 0;
#pragma unroll
    for (int i = 0; i < 16; ++i) {
        uint32_t s = 0;
#pragma unroll
        for (int k = 0; k < H_COPIES; ++k) s += hist[(k << 12) + t * 16 + i];
        bv[i] = s; ct += s;
    }
    sfx[t] = ct;
    __syncthreads();
    for (int off = 1; off < 256; off <<= 1) {
        uint32_t v = (t + off < 256) ? sfx[t + off] : 0;
        __syncthreads();
        sfx[t] += v;
        __syncthreads();
    }
    if (sfx[t] >= (uint32_t)K_TOP && (t == 255 || sfx[t + 1] < (uint32_t)K_TOP)) {
        uint32_t cum = (t == 255) ? 0u : sfx[t + 1];
        int i = 15;
        for (; i >= 0; --i) { cum += bv[i]; if (cum >= (uint32_t)K_TOP) break; }
        if (i < 0) i = 0;
        uint32_t bstar = (uint32_t)(t * 16 + i);
        uint32_t tk = bstar << 20;
        // δ-ULP margin: covers rounded-sigmoid ties (~11 key-ULPs) with 370x slack.
        sTk = (tk > DELTA_ULP) ? (tk - DELTA_ULP) : 0u;
    }
    __syncthreads();
    uint32_t Tk = sTk;

    const uint4* m4 = (const uint4*)mkey;
    size_t base = (size_t)blockIdx.x * 1024;       // uint4 index; 4096 rows/block
    for (int it = 0; it < 4; ++it) {
        uint32_t r0 = (uint32_t)((base + it * 256 + t) * 4);
        uint4 v = m4[base + it * 256 + t];
#pragma unroll
        for (int e = 0; e < 4; ++e) {
            uint32_t u = (e == 0) ? v.x : (e == 1) ? v.y : (e == 2) ? v.z : v.w;
            bool pass = u >= Tk;
            unsigned long long bal = __ballot(pass);
            if (bal) {
                uint32_t wbase = 0;
                if (lane == 0) wbase = atomicAdd(&cnt, (uint32_t)__popcll(bal));
                wbase = __shfl(wbase, 0);
                if (pass) {
                    uint32_t pos = wbase + (uint32_t)__popcll(bal & ((1ull << lane) - 1ull));
                    if (pos < 1024) {
                        float m = mono_inv(u);
                        float ef = (float)exp(-(double)m);   // ~correctly-rounded fp32 expf
                        float s = 1.0f / (1.0f + ef);
                        stg[pos] = ((uint64_t)(~__float_as_uint(s)) << 32) | (r0 + e);
                    }
                }
            }
        }
    }
    __syncthreads();
    uint32_t n = cnt; if (n > 1024) n = 1024;
    if (t == 0 && n) gbase = atomicAdd(&scal[SC_CNT], n);
    __syncthreads();
    if (n) {
        uint32_t gb = gbase;
        for (uint32_t i = t; i < n; i += 256) {
            uint32_t pos = gb + i;
            if (pos < (uint32_t)CAND_MAX) cand[pos] = stg[i];  // plain store; boundary = coherence
        }
    }
}

// ---- D3: rank-by-counting, M-insensitive version (R10 fix): cand[] already holds
//      final keys -> LDS fill is a straight copy (no exp). 256 blocks x 4 waves =
//      1024 waves (~4 candidates each); inner scan 4-way unrolled for LDS ILP.
__global__ __launch_bounds__(256) void k_rank(const unsigned long long* __restrict__ cand,
                                              uint32_t* __restrict__ scal,
                                              const float* __restrict__ deltas,
                                              const float* __restrict__ locs,
                                              const int* __restrict__ stridep,
                                              const uint8_t* __restrict__ cls,
                                              float* __restrict__ out) {
    __shared__ uint64_t keys[CAND_MAX];   // 64 KB
    int t = threadIdx.x;
    uint32_t M = scal[SC_CNT];
    if (M > (uint32_t)CAND_MAX) M = CAND_MAX;
    for (uint32_t i = t; i < M; i += 256) keys[i] = cand[i];
    __syncthreads();
    int wid = t >> 6, lane = t & 63;
    float stridef = (float)(*stridep);
    float wmx = -3.4e38f;
    for (uint32_t c = (uint32_t)blockIdx.x * 4 + wid; c < M; c += 1024) {
        uint64_t myk = keys[c];
        uint32_t r = 0;
        uint32_t j = lane;
        for (; j + 192 < M; j += 256) {             // 4 independent LDS reads -> pipelined
            uint64_t k0 = keys[j], k1 = keys[j + 64], k2 = keys[j + 128], k3 = keys[j + 192];
            r += (uint32_t)(k0 < myk) + (uint32_t)(k1 < myk)
               + (uint32_t)(k2 < myk) + (uint32_t)(k3 < myk);
        }
        for (; j < M; j += 64) r += (keys[j] < myk) ? 1u : 0u;
#pragma unroll
        for (int o = 32; o > 0; o >>= 1) r += __shfl_down(r, o);
        if (lane == 0 && r < (uint32_t)K_TOP) {
            uint32_t row = (uint32_t)myk & (N_ROWS - 1);
            float s = __uint_as_float(~(uint32_t)(myk >> 32));
            float4 dl = ((const float4*)deltas)[row];
            float2 lc = ((const float2*)locs)[row];
            float d0 = dl.x * stridef, d1 = dl.y * stridef, d2 = dl.z * stridef, d3 = dl.w * stridef;
            float b0f = lc.x - d0, b1f = lc.y - d1, b2f = lc.x + d2, b3f = lc.y + d3;
            float4 bx = { b0f, b1f, b2f, b3f };
            *(float4*)&out[4 * r] = bx;
            out[8000 + r] = s;
            out[10000 + r] = (float)cls[row];
            wmx = fmaxf(wmx, fmaxf(fmaxf(b0f, b1f), fmaxf(b2f, b3f)));
        }
    }
    if (lane == 0) atomicMax(&scal[SC_MAXK], mono_key(wmx));
}

// ---- D4: pairwise suppression mask (quirky IoU replicated exactly) + fused scan.
//      Skip-empty rows (grp-gated). Atomic-only handoff (proven R5/R7/R8). Tail: zin reset.
__global__ __launch_bounds__(256) void k_maskscan(const float* __restrict__ out_ro,
                                                  uint32_t* __restrict__ scal,
                                                  uint64_t* __restrict__ mask,
                                                  unsigned long long* __restrict__ grp,
                                                  uint32_t* __restrict__ zin,
                                                  float* __restrict__ out) {
    __shared__ uint64_t wb[4][32];
    __shared__ int lastdone;
    int t = threadIdx.x;
    int lane = t & 63;
    int wid = t >> 6;
    int i = blockIdx.x * 4 + wid;                   // 2000 waves total
    float off1 = mono_inv(scal[SC_MAXK]) + 1.0f;    // max_coord + 1 (prev dispatch, coherent)
    float4 boxi = *(const float4*)&out_ro[4 * i];
    float oi = out_ro[10000 + i] * off1;
    float x1i = boxi.x + oi, y2i = boxi.y + oi, x2i = boxi.z + oi, y1i = boxi.w + oi;
    float ai = (x2i - x1i) * (y2i - y1i);
    uint64_t any = 0;
    for (int jb = 0; jb < 32; ++jb) {
        int j = jb * 64 + lane;
        bool sup = false;
        if (j < K_TOP && j > i) {
            float4 boxj = *(const float4*)&out_ro[4 * j];
            float oj = out_ro[10000 + j] * off1;
            float x1j = boxj.x + oj, y2j = boxj.y + oj, x2j = boxj.z + oj, y1j = boxj.w + oj;
            float aj = (x2j - x1j) * (y2j - y1j);
            float xx1 = fmaxf(x1i, x1j);
            float yy1 = fminf(y1i, y1j);
            float xx2 = fminf(x2i, x2j);
            float yy2 = fmaxf(y2i, y2j);
            float inter = fabsf(xx2 - xx1) * fabsf(yy2 - yy1);
            float iou = inter / ((ai + aj) - inter);
            sup = iou > 0.5f;
        }
        unsigned long long bits = __ballot(sup);
        if (lane == 0) wb[wid][jb] = bits;
        any |= bits;
    }
    unsigned long long dummy = 0;
    if (lane == 0 && any) {                         // rare: NMS barely suppresses here
        for (int jb = 0; jb < 32; ++jb)
            dummy += atomicExch(&mask[(size_t)i * 32 + jb], wb[wid][jb]);
        dummy += atomicOr(&grp[i >> 6], 1ull << (i & 63));
    }
    asm volatile("" :: "v"(dummy));                 // force atomic returns (vmcnt drained)
    asm volatile("s_waitcnt vmcnt(0) lgkmcnt(0)" ::: "memory");
    __syncthreads();
    if (t == 0) {
        unsigned old = atomicAdd(&scal[SC_DONE], 1u);
        lastdone = (old == (unsigned)(gridDim.x - 1)) ? 1 : 0;
    }
    __syncthreads();
    if (!lastdone) return;

    if (t < 64) {
        int l = t;                                  // lane w<32 holds active word w
        uint64_t g = (l < 32) ? atomicOr(&grp[l], 0ull) : 0ull;
        uint64_t active = ~0ull;
        if (__ballot(g != 0ull)) {
            for (int gg = 0; gg < 32; ++gg) {
                uint64_t nz = __shfl(g, gg);
                while (nz) {
                    int b = __ffsll((long long)nz) - 1;
                    nz &= nz - 1;
                    int ii = gg * 64 + b;
                    uint64_t aw = __shfl(active, gg);
                    bool kept = (aw >> b) & 1ull;
                    uint64_t m = (l < 32) ? atomicOr(&mask[(size_t)ii * 32 + l], 0ull) : 0ull;
                    if (kept) active &= ~m;
                }
            }
        }
        if (l < 32) {
            int limit = K_TOP - l * 64;
            int nvec = limit < 64 ? limit / 4 : 16;
            for (int v = 0; v < nvec; ++v) {
                float4 f;
                f.x = ((active >> (4 * v + 0)) & 1ull) ? 1.0f : 0.0f;
                f.y = ((active >> (4 * v + 1)) & 1ull) ? 1.0f : 0.0f;
                f.z = ((active >> (4 * v + 2)) & 1ull) ? 1.0f : 0.0f;
                f.w = ((active >> (4 * v + 3)) & 1ull) ? 1.0f : 0.0f;
                *(float4*)&out[12000 + l * 64 + 4 * v] = f;
            }
        }
    }
    // reset MAGIC words for the next replay (zeroed state is what D1 expects)
    if (t < 8) atomicExch(&zin[t], 0u);
}

extern "C" void kernel_launch(void* const* d_in, const int* in_sizes, int n_in,
                              void* d_out, int out_size, void* d_ws, size_t ws_size,
                              hipStream_t stream) {
    const float* deltas = (const float*)d_in[0];
    const float* locs   = (const float*)d_in[1];
    const float* logits = (const float*)d_in[2];
    const int*   stridep = (const int*)d_in[3];
    float* out = (float*)d_out;
    char* ws = (char*)d_ws;

    uint32_t* mkey = (uint32_t*)(ws + OFF_MKEY);
    uint8_t*  cls  = (uint8_t*)(ws + OFF_CLS);
    uint32_t* hist = (uint32_t*)(ws + OFF_HIST);
    uint32_t* scal = (uint32_t*)(ws + OFF_SCAL);
    unsigned long long* grp = (unsigned long long*)(ws + OFF_GRP);
    uint32_t* zin  = (uint32_t*)(ws + OFF_ZIN);
    unsigned long long* cand = (unsigned long long*)(ws + OFF_CAND);
    uint64_t* mask = (uint64_t*)(ws + OFF_MASK);

    k_score<<<dim3(1024), dim3(256), 0, stream>>>(logits, mkey, cls, hist, zin);
    k_compact<<<dim3(256), dim3(256), 0, stream>>>(mkey, hist, scal, cand);
    k_rank<<<dim3(256), dim3(256), 0, stream>>>(cand, scal, deltas, locs, stridep, cls, out);
    k_maskscan<<<dim3(500), dim3(256), 0, stream>>>(out, scal, mask, grp, zin, out);
}

// Round 12
// 106.429 us; speedup vs baseline: 1.5644x; 1.0144x over previous
//
#include <hip/hip_runtime.h>
#include <stdint.h>
#include <math.h>

#pragma clang fp contract(off)

#define N_ROWS 1048576
#define N_CLS  20
#define K_TOP  2000
#define CAND_MAX 8192
#define NBINS  4096
#define H_COPIES 4
#define DELTA_ULP 4096u
#define MAGIC 0x5AD0C0DEu

// scal slots (dwords) -- inside the zeroed region
#define SC_CNT   0
#define SC_MAXK  1
#define SC_DONE  2   // maskscan done-counter

// ws layout
static constexpr size_t OFF_MKEY = 0;                              // u32[N]          4 MB
static constexpr size_t OFF_CLS  = OFF_MKEY + 4ull * N_ROWS;       // u8[N]           1 MB
static constexpr size_t OFF_HIST = OFF_CLS + (size_t)N_ROWS;       // u32[4*4096] -- zero region start
static constexpr size_t OFF_SCAL = OFF_HIST + 4ull * H_COPIES * NBINS;  // u32[16]
static constexpr size_t OFF_GRP  = OFF_SCAL + 64;                  // u64[32]     -- zero region end (16464 dw)
static constexpr size_t OFF_ZIN  = OFF_GRP + 256;                  // u32[8] MAGIC words (reset by last kernel)
static constexpr size_t OFF_CAND = OFF_ZIN + 64;                   // u64[CAND_MAX]
static constexpr size_t OFF_MASK = OFF_CAND + 8ull * CAND_MAX;     // u64[K_TOP*32]

__device__ __forceinline__ uint32_t mono_key(float f) {
    uint32_t u = __float_as_uint(f);
    return u ^ ((u & 0x80000000u) ? 0xFFFFFFFFu : 0x80000000u);
}
__device__ __forceinline__ float mono_inv(uint32_t k) {
    uint32_t u = (k & 0x80000000u) ? (k ^ 0x80000000u) : ~k;
    return __uint_as_float(u);
}

// ---- D1: per-row max/argmax of logits -> mkey, cls, fused 12-bit histogram.
//      DIRECT per-row loads (5x float4/lane, wave covers contiguous 5KB -- BW-clean):
//      no LDS staging, no in-loop barriers, LDS = hh[4096] only (16 KB) ->
//      8 blocks/CU (wave-capped), 32 waves/CU, deep MLP. R11 post-mortem: the staged
//      version's 37.5KB LDS + 8 barriers/block + scatter conflicts cost ~3.5x.
__global__ __launch_bounds__(256) void k_score(const float* __restrict__ logits,
                                               uint32_t* __restrict__ mkey,
                                               uint8_t* __restrict__ cls,
                                               uint32_t* __restrict__ hist,   // zero region base
                                               uint32_t* __restrict__ zin) {
    __shared__ uint32_t hh[NBINS];         // 16 KB
    int t = threadIdx.x, b = blockIdx.x;

    // zero phase: blocks 0..7 zero hist(16384 dw) + scal(16) + grp(64) via device atomics
    if (b < 8) {
        uint32_t zd = 0;
        for (int k = 0; k < 8; ++k) zd += atomicExch(&hist[(b * 256 + t) + k * 2048], 0u);
        if (b == 7 && t < 80) zd += atomicExch(&hist[16384 + t], 0u);
        asm volatile("" :: "v"(zd));
        asm volatile("s_waitcnt vmcnt(0)" ::: "memory");
        __syncthreads();
        if (t == 0) atomicExch(&zin[b], MAGIC);
    }

    for (int i = t; i < NBINS; i += 256) hh[i] = 0;
    __syncthreads();

    size_t rowbase0 = (size_t)b * 1024;
#pragma unroll
    for (int g = 0; g < 4; ++g) {
        size_t ri = rowbase0 + (size_t)g * 256 + t;
        const float4* p = (const float4*)(logits + ri * N_CLS);
        float4 v0 = p[0], v1 = p[1], v2 = p[2], v3 = p[3], v4 = p[4];  // 5 indep loads
        float m = v0.x; int ci = 0;
        float vv[20] = { v0.x, v0.y, v0.z, v0.w, v1.x, v1.y, v1.z, v1.w,
                         v2.x, v2.y, v2.z, v2.w, v3.x, v3.y, v3.z, v3.w,
                         v4.x, v4.y, v4.z, v4.w };
#pragma unroll
        for (int c = 1; c < 20; ++c) {
            if (vv[c] > m) { m = vv[c]; ci = c; }   // first-max-wins == jnp.argmax
        }
        uint32_t u = mono_key(m);
        mkey[ri] = u;
        cls[ri] = (uint8_t)ci;
        atomicAdd(&hh[u >> 20], 1u);                // 12-bit bin
    }
    __syncthreads();

    // wait for zeroing (normally long done: zero ~1us << compute ~13us)
    for (;;) {
        int ok = 1;
        if (t < 8) ok = (atomicAdd(&zin[t], 0u) == MAGIC) ? 1 : 0;
        if (__syncthreads_count(ok) == 256) break;
        __builtin_amdgcn_s_sleep(16);
    }
    // publish nonzero bins only (4 spread copies); kernel-end drain handles visibility
    uint32_t cp = (uint32_t)((b & (H_COPIES - 1)) << 12);
    for (int i = 0; i < 16; ++i) {
        uint32_t v = hh[t * 16 + i];
        if (v) atomicAdd(&hist[cp + t * 16 + i], v);
    }
}

// ---- D2: per-block redundant 12-bit find -> Tk = (b*<<20) - DELTA_ULP (tie margin),
//      then compact candidates (mkey >= Tk). cand[] stores the FINAL sort key
//      ((~sigmoid_bits)<<32 | row) -- sigmoid computed here only for passing rows.
__global__ __launch_bounds__(256) void k_compact(const uint32_t* __restrict__ mkey,
                                                 const uint32_t* __restrict__ hist,
                                                 uint32_t* __restrict__ scal,
                                                 unsigned long long* __restrict__ cand) {
    __shared__ uint32_t sfx[256];
    __shared__ uint32_t sTk;
    __shared__ uint32_t cnt, gbase;
    __shared__ uint64_t stg[1024];
    int t = threadIdx.x;
    int lane = t & 63;
    if (t == 0) cnt = 0;

    // find12: thread t owns bins [t*16, t*16+16), summed over 4 copies; suffix-scan
    // over 256 chunk totals; locate rank-K bin.
    uint32_t bv[16]; uint32_t ct = 0;
#pragma unroll
    for (int i = 0; i < 16; ++i) {
        uint32_t s = 0;
#pragma unroll
        for (int k = 0; k < H_COPIES; ++k) s += hist[(k << 12) + t * 16 + i];
        bv[i] = s; ct += s;
    }
    sfx[t] = ct;
    __syncthreads();
    for (int off = 1; off < 256; off <<= 1) {
        uint32_t v = (t + off < 256) ? sfx[t + off] : 0;
        __syncthreads();
        sfx[t] += v;
        __syncthreads();
    }
    if (sfx[t] >= (uint32_t)K_TOP && (t == 255 || sfx[t + 1] < (uint32_t)K_TOP)) {
        uint32_t cum = (t == 255) ? 0u : sfx[t + 1];
        int i = 15;
        for (; i >= 0; --i) { cum += bv[i]; if (cum >= (uint32_t)K_TOP) break; }
        if (i < 0) i = 0;
        uint32_t bstar = (uint32_t)(t * 16 + i);
        uint32_t tk = bstar << 20;
        // δ-ULP margin: covers rounded-sigmoid ties (~11 key-ULPs) with 370x slack.
        sTk = (tk > DELTA_ULP) ? (tk - DELTA_ULP) : 0u;
    }
    __syncthreads();
    uint32_t Tk = sTk;

    const uint4* m4 = (const uint4*)mkey;
    size_t base = (size_t)blockIdx.x * 1024;       // uint4 index; 4096 rows/block
    for (int it = 0; it < 4; ++it) {
        uint32_t r0 = (uint32_t)((base + it * 256 + t) * 4);
        uint4 v = m4[base + it * 256 + t];
#pragma unroll
        for (int e = 0; e < 4; ++e) {
            uint32_t u = (e == 0) ? v.x : (e == 1) ? v.y : (e == 2) ? v.z : v.w;
            bool pass = u >= Tk;
            unsigned long long bal = __ballot(pass);
            if (bal) {
                uint32_t wbase = 0;
                if (lane == 0) wbase = atomicAdd(&cnt, (uint32_t)__popcll(bal));
                wbase = __shfl(wbase, 0);
                if (pass) {
                    uint32_t pos = wbase + (uint32_t)__popcll(bal & ((1ull << lane) - 1ull));
                    if (pos < 1024) {
                        float m = mono_inv(u);
                        float ef = (float)exp(-(double)m);   // ~correctly-rounded fp32 expf
                        float s = 1.0f / (1.0f + ef);
                        stg[pos] = ((uint64_t)(~__float_as_uint(s)) << 32) | (r0 + e);
                    }
                }
            }
        }
    }
    __syncthreads();
    uint32_t n = cnt; if (n > 1024) n = 1024;
    if (t == 0 && n) gbase = atomicAdd(&scal[SC_CNT], n);
    __syncthreads();
    if (n) {
        uint32_t gb = gbase;
        for (uint32_t i = t; i < n; i += 256) {
            uint32_t pos = gb + i;
            if (pos < (uint32_t)CAND_MAX) cand[pos] = stg[i];  // plain store; boundary = coherence
        }
    }
}

// ---- D3: rank-by-counting, M-insensitive (proven R11): cand[] already holds final
//      keys -> LDS fill is a straight copy. 256 blocks x 4 waves; inner scan 4-way
//      unrolled for LDS ILP.
__global__ __launch_bounds__(256) void k_rank(const unsigned long long* __restrict__ cand,
                                              uint32_t* __restrict__ scal,
                                              const float* __restrict__ deltas,
                                              const float* __restrict__ locs,
                                              const int* __restrict__ stridep,
                                              const uint8_t* __restrict__ cls,
                                              float* __restrict__ out) {
    __shared__ uint64_t keys[CAND_MAX];   // 64 KB
    int t = threadIdx.x;
    uint32_t M = scal[SC_CNT];
    if (M > (uint32_t)CAND_MAX) M = CAND_MAX;
    for (uint32_t i = t; i < M; i += 256) keys[i] = cand[i];
    __syncthreads();
    int wid = t >> 6, lane = t & 63;
    float stridef = (float)(*stridep);
    float wmx = -3.4e38f;
    for (uint32_t c = (uint32_t)blockIdx.x * 4 + wid; c < M; c += 1024) {
        uint64_t myk = keys[c];
        uint32_t r = 0;
        uint32_t j = lane;
        for (; j + 192 < M; j += 256) {             // 4 independent LDS reads -> pipelined
            uint64_t k0 = keys[j], k1 = keys[j + 64], k2 = keys[j + 128], k3 = keys[j + 192];
            r += (uint32_t)(k0 < myk) + (uint32_t)(k1 < myk)
               + (uint32_t)(k2 < myk) + (uint32_t)(k3 < myk);
        }
        for (; j < M; j += 64) r += (keys[j] < myk) ? 1u : 0u;
#pragma unroll
        for (int o = 32; o > 0; o >>= 1) r += __shfl_down(r, o);
        if (lane == 0 && r < (uint32_t)K_TOP) {
            uint32_t row = (uint32_t)myk & (N_ROWS - 1);
            float s = __uint_as_float(~(uint32_t)(myk >> 32));
            float4 dl = ((const float4*)deltas)[row];
            float2 lc = ((const float2*)locs)[row];
            float d0 = dl.x * stridef, d1 = dl.y * stridef, d2 = dl.z * stridef, d3 = dl.w * stridef;
            float b0f = lc.x - d0, b1f = lc.y - d1, b2f = lc.x + d2, b3f = lc.y + d3;
            float4 bx = { b0f, b1f, b2f, b3f };
            *(float4*)&out[4 * r] = bx;
            out[8000 + r] = s;
            out[10000 + r] = (float)cls[row];
            wmx = fmaxf(wmx, fmaxf(fmaxf(b0f, b1f), fmaxf(b2f, b3f)));
        }
    }
    if (lane == 0) atomicMax(&scal[SC_MAXK], mono_key(wmx));
}

// ---- D4: pairwise suppression mask (quirky IoU replicated exactly) + fused scan.
//      Skip-empty rows (grp-gated). Atomic-only handoff (proven R5/R7/R8). Tail: zin reset.
__global__ __launch_bounds__(256) void k_maskscan(const float* __restrict__ out_ro,
                                                  uint32_t* __restrict__ scal,
                                                  uint64_t* __restrict__ mask,
                                                  unsigned long long* __restrict__ grp,
                                                  uint32_t* __restrict__ zin,
                                                  float* __restrict__ out) {
    __shared__ uint64_t wb[4][32];
    __shared__ int lastdone;
    int t = threadIdx.x;
    int lane = t & 63;
    int wid = t >> 6;
    int i = blockIdx.x * 4 + wid;                   // 2000 waves total
    float off1 = mono_inv(scal[SC_MAXK]) + 1.0f;    // max_coord + 1 (prev dispatch, coherent)
    float4 boxi = *(const float4*)&out_ro[4 * i];
    float oi = out_ro[10000 + i] * off1;
    float x1i = boxi.x + oi, y2i = boxi.y + oi, x2i = boxi.z + oi, y1i = boxi.w + oi;
    float ai = (x2i - x1i) * (y2i - y1i);
    uint64_t any = 0;
    for (int jb = 0; jb < 32; ++jb) {
        int j = jb * 64 + lane;
        bool sup = false;
        if (j < K_TOP && j > i) {
            float4 boxj = *(const float4*)&out_ro[4 * j];
            float oj = out_ro[10000 + j] * off1;
            float x1j = boxj.x + oj, y2j = boxj.y + oj, x2j = boxj.z + oj, y1j = boxj.w + oj;
            float aj = (x2j - x1j) * (y2j - y1j);
            float xx1 = fmaxf(x1i, x1j);
            float yy1 = fminf(y1i, y1j);
            float xx2 = fminf(x2i, x2j);
            float yy2 = fmaxf(y2i, y2j);
            float inter = fabsf(xx2 - xx1) * fabsf(yy2 - yy1);
            float iou = inter / ((ai + aj) - inter);
            sup = iou > 0.5f;
        }
        unsigned long long bits = __ballot(sup);
        if (lane == 0) wb[wid][jb] = bits;
        any |= bits;
    }
    unsigned long long dummy = 0;
    if (lane == 0 && any) {                         // rare: NMS barely suppresses here
        for (int jb = 0; jb < 32; ++jb)
            dummy += atomicExch(&mask[(size_t)i * 32 + jb], wb[wid][jb]);
        dummy += atomicOr(&grp[i >> 6], 1ull << (i & 63));
    }
    asm volatile("" :: "v"(dummy));                 // force atomic returns (vmcnt drained)
    asm volatile("s_waitcnt vmcnt(0) lgkmcnt(0)" ::: "memory");
    __syncthreads();
    if (t == 0) {
        unsigned old = atomicAdd(&scal[SC_DONE], 1u);
        lastdone = (old == (unsigned)(gridDim.x - 1)) ? 1 : 0;
    }
    __syncthreads();
    if (!lastdone) return;

    if (t < 64) {
        int l = t;                                  // lane w<32 holds active word w
        uint64_t g = (l < 32) ? atomicOr(&grp[l], 0ull) : 0ull;
        uint64_t active = ~0ull;
        if (__ballot(g != 0ull)) {
            for (int gg = 0; gg < 32; ++gg) {
                uint64_t nz = __shfl(g, gg);
                while (nz) {
                    int b = __ffsll((long long)nz) - 1;
                    nz &= nz - 1;
                    int ii = gg * 64 + b;
                    uint64_t aw = __shfl(active, gg);
                    bool kept = (aw >> b) & 1ull;
                    uint64_t m = (l < 32) ? atomicOr(&mask[(size_t)ii * 32 + l], 0ull) : 0ull;
                    if (kept) active &= ~m;
                }
            }
        }
        if (l < 32) {
            int limit = K_TOP - l * 64;
            int nvec = limit < 64 ? limit / 4 : 16;
            for (int v = 0; v < nvec; ++v) {
                float4 f;
                f.x = ((active >> (4 * v + 0)) & 1ull) ? 1.0f : 0.0f;
                f.y = ((active >> (4 * v + 1)) & 1ull) ? 1.0f : 0.0f;
                f.z = ((active >> (4 * v + 2)) & 1ull) ? 1.0f : 0.0f;
                f.w = ((active >> (4 * v + 3)) & 1ull) ? 1.0f : 0.0f;
                *(float4*)&out[12000 + l * 64 + 4 * v] = f;
            }
        }
    }
    // reset MAGIC words for the next replay (zeroed state is what D1 expects)
    if (t < 8) atomicExch(&zin[t], 0u);
}

extern "C" void kernel_launch(void* const* d_in, const int* in_sizes, int n_in,
                              void* d_out, int out_size, void* d_ws, size_t ws_size,
                              hipStream_t stream) {
    const float* deltas = (const float*)d_in[0];
    const float* locs   = (const float*)d_in[1];
    const float* logits = (const float*)d_in[2];
    const int*   stridep = (const int*)d_in[3];
    float* out = (float*)d_out;
    char* ws = (char*)d_ws;

    uint32_t* mkey = (uint32_t*)(ws + OFF_MKEY);
    uint8_t*  cls  = (uint8_t*)(ws + OFF_CLS);
    uint32_t* hist = (uint32_t*)(ws + OFF_HIST);
    uint32_t* scal = (uint32_t*)(ws + OFF_SCAL);
    unsigned long long* grp = (unsigned long long*)(ws + OFF_GRP);
    uint32_t* zin  = (uint32_t*)(ws + OFF_ZIN);
    unsigned long long* cand = (unsigned long long*)(ws + OFF_CAND);
    uint64_t* mask = (uint64_t*)(ws + OFF_MASK);

    k_score<<<dim3(1024), dim3(256), 0, stream>>>(logits, mkey, cls, hist, zin);
    k_compact<<<dim3(256), dim3(256), 0, stream>>>(mkey, hist, scal, cand);
    k_rank<<<dim3(256), dim3(256), 0, stream>>>(cand, scal, deltas, locs, stridep, cls, out);
    k_maskscan<<<dim3(500), dim3(256), 0, stream>>>(out, scal, mask, grp, zin, out);
}